// Round 4
// baseline (8200.279 us; speedup 1.0000x reference)
//
#include <hip/hip_runtime.h>
#include <hip/hip_bf16.h>

// ---------------- constants ----------------
#define TB 4
#define TT 2048
#define DIN 513
#define TOUT 509
#define M2 2036          // TB*TOUT
#define DM 512
#define PR 4096
#define DIc 1024
#define Hh 16
#define CONVD 1152
#define DINP 2192        // 2*DIc + 2*64 + 16
#define ZLD 4384         // 2*DINP (fw|bw stacked)

// ---------------- day-specific input transform ----------------
// hfull[b,t,n] = softsign(sum_d x[b,t,d] * day_w[day[b],d,n] + day_b[day[b],n]), n<512
__global__ __launch_bounds__(256) void day_gemm(const float* __restrict__ x,
                                                const int* __restrict__ day_idx,
                                                const float* __restrict__ day_w,
                                                const float* __restrict__ day_b,
                                                float* __restrict__ hfull) {
    int b = blockIdx.z;
    int day = day_idx[b];
    int n0 = blockIdx.x * 64, m0 = blockIdx.y * 64;
    int tid = threadIdx.x;
    __shared__ float As[16][68], Bs[16][68];
    float acc[4][4] = {};
    int tm = tid >> 4, tn = tid & 15;
    int lrow = tid >> 2, lk = (tid & 3) * 4;
    const float* Ab = x + ((size_t)b * TT + m0) * DIN;
    const float* Bb = day_w + (size_t)day * 512 * 512;
    for (int k0 = 0; k0 < 512; k0 += 16) {
        #pragma unroll
        for (int j = 0; j < 4; j++)
            As[lk + j][lrow] = Ab[(size_t)lrow * DIN + k0 + lk + j];
        int kb = tid >> 4; int nb = (tid & 15) * 4;
        #pragma unroll
        for (int j = 0; j < 4; j++)
            Bs[kb][nb + j] = Bb[(size_t)(k0 + kb) * 512 + n0 + nb + j];
        __syncthreads();
        #pragma unroll
        for (int kk = 0; kk < 16; kk++) {
            float4 av = *(const float4*)&As[kk][tm * 4];
            float4 bv = *(const float4*)&Bs[kk][tn * 4];
            float a[4] = {av.x, av.y, av.z, av.w};
            float bb2[4] = {bv.x, bv.y, bv.z, bv.w};
            #pragma unroll
            for (int i = 0; i < 4; i++)
                #pragma unroll
                for (int j = 0; j < 4; j++) acc[i][j] += a[i] * bb2[j];
        }
        __syncthreads();
    }
    #pragma unroll
    for (int i = 0; i < 4; i++) {
        int m = m0 + tm * 4 + i;
        #pragma unroll
        for (int j = 0; j < 4; j++) {
            int n = n0 + tn * 4 + j;
            float v = acc[i][j] + day_b[day * 512 + n];
            v = v / (1.f + fabsf(v));
            hfull[((size_t)b * TT + m) * DIN + n] = v;
        }
    }
}

__global__ void copy_xt(const float* __restrict__ x, float* __restrict__ hfull) {
    int idx = blockIdx.x * 256 + threadIdx.x;
    if (idx >= TB * TT) return;
    hfull[(size_t)idx * DIN + 512] = x[(size_t)idx * DIN + 512];
}

// ---------------- generic GEMM: C[M,N] = act(A @ Bw^T + bias) (+= C) ----------------
// A: f32, row offset = (m/rowDiv)*sOuter + (m%rowDiv)*sInner
// Bw: f32 [N,K] row-major
template <int ACT, int ACCUM>
__global__ __launch_bounds__(256) void gemm_k(const float* __restrict__ A,
                                              const float* __restrict__ Bw,
                                              const float* __restrict__ bias,
                                              float* __restrict__ C,
                                              int M, int N, int K,
                                              int rowDiv, long sOuter, long sInner, int ldc) {
    int n0 = blockIdx.x * 64, m0 = blockIdx.y * 64;
    int tid = threadIdx.x;
    __shared__ float As[16][68], Bs[16][68];
    float acc[4][4] = {};
    int tm = tid >> 4, tn = tid & 15;
    int lrow = tid >> 2, lk = (tid & 3) * 4;
    int am = m0 + lrow;
    bool avalid = am < M;
    int amc = avalid ? am : 0;
    long abase = (long)(amc / rowDiv) * sOuter + (long)(amc % rowDiv) * sInner;
    int bn = n0 + lrow;
    bool bvalid = bn < N;
    long bbase = (long)(bvalid ? bn : 0) * K;
    for (int k0 = 0; k0 < K; k0 += 16) {
        if (avalid && (k0 + lk + 3) < K) {
            float4 av = *(const float4*)(A + abase + k0 + lk);
            As[lk][lrow] = av.x; As[lk + 1][lrow] = av.y;
            As[lk + 2][lrow] = av.z; As[lk + 3][lrow] = av.w;
        } else {
            #pragma unroll
            for (int j = 0; j < 4; j++) {
                int k = k0 + lk + j;
                As[lk + j][lrow] = (avalid && k < K) ? A[abase + k] : 0.f;
            }
        }
        #pragma unroll
        for (int j = 0; j < 4; j++) {
            int k = k0 + lk + j;
            Bs[lk + j][lrow] = (bvalid && k < K) ? Bw[bbase + k] : 0.f;
        }
        __syncthreads();
        #pragma unroll
        for (int kk = 0; kk < 16; kk++) {
            float4 av = *(const float4*)&As[kk][tm * 4];
            float4 bv = *(const float4*)&Bs[kk][tn * 4];
            float a[4] = {av.x, av.y, av.z, av.w};
            float bb2[4] = {bv.x, bv.y, bv.z, bv.w};
            #pragma unroll
            for (int i = 0; i < 4; i++)
                #pragma unroll
                for (int j = 0; j < 4; j++) acc[i][j] += a[i] * bb2[j];
        }
        __syncthreads();
    }
    #pragma unroll
    for (int i = 0; i < 4; i++) {
        int m = m0 + tm * 4 + i;
        if (m >= M) continue;
        #pragma unroll
        for (int j = 0; j < 4; j++) {
            int n = n0 + tn * 4 + j;
            if (n >= N) continue;
            float v = acc[i][j];
            if (bias) v += bias[n];
            if (ACT == 1) v = v / (1.f + fabsf(v));
            long ci = (long)m * ldc + n;
            if (ACCUM) v += C[ci];
            C[ci] = v;
        }
    }
}

// ---------------- LayerNorm ----------------
__global__ __launch_bounds__(64) void ln_kernel(const float* __restrict__ h,
                                                const float* __restrict__ w,
                                                const float* __restrict__ bgain,
                                                float* __restrict__ hn) {
    int m = blockIdx.x, lane = threadIdx.x;
    const float* row = h + (size_t)m * DM;
    float v[8]; float s = 0.f;
    #pragma unroll
    for (int j = 0; j < 8; j++) { v[j] = row[lane + j * 64]; s += v[j]; }
    for (int o = 1; o < 64; o <<= 1) s += __shfl_xor(s, o);
    float mu = s * (1.f / DM);
    float var = 0.f;
    #pragma unroll
    for (int j = 0; j < 8; j++) { float d = v[j] - mu; var += d * d; }
    for (int o = 1; o < 64; o <<= 1) var += __shfl_xor(var, o);
    float inv = rsqrtf(var * (1.f / DM) + 1e-5f);
    #pragma unroll
    for (int j = 0; j < 8; j++) {
        int c = lane + j * 64;
        hn[(size_t)m * DM + c] = (v[j] - mu) * inv * w[c] + bgain[c];
    }
}

// ---------------- depthwise conv (dir-aware) + SiLU ----------------
__global__ void conv_kernel(const float* __restrict__ zx2,
                            const float* __restrict__ cw,
                            const float* __restrict__ cb,
                            float* __restrict__ xbcc) {
    int idx = blockIdx.x * 256 + threadIdx.x;
    if (idx >= 2 * M2 * CONVD) return;
    int dir = idx / (M2 * CONVD);
    int r = idx - dir * (M2 * CONVD);
    int m = r / CONVD; int c = r - m * CONVD;
    int b = m / TOUT; int t = m - b * TOUT;
    float acc = cb[dir * CONVD + c];
    const float* w = cw + (size_t)(dir * CONVD + c) * 4;
    #pragma unroll
    for (int k = 0; k < 4; k++) {
        int tp = dir ? (t + 3 - k) : (t - 3 + k);
        if (tp >= 0 && tp < TOUT)
            acc += w[k] * zx2[(size_t)(b * TOUT + tp) * ZLD + dir * DINP + DIc + c];
    }
    xbcc[(size_t)idx] = acc / (1.f + expf(-acc));   // silu
}

// ---------------- dt softplus + dA ----------------
__global__ void dt_kernel(const float* __restrict__ zx2,
                          const float* __restrict__ dtB,
                          const float* __restrict__ alog,
                          float* __restrict__ dtb, float* __restrict__ dab) {
    int idx = blockIdx.x * 256 + threadIdx.x;
    if (idx >= 2 * M2 * Hh) return;
    int dir = idx / (M2 * Hh);
    int r = idx - dir * (M2 * Hh);
    int m = r / Hh; int hh = r - m * Hh;
    float raw = zx2[(size_t)m * ZLD + dir * DINP + DIc + CONVD + hh] + dtB[dir * Hh + hh];
    float sp = raw > 20.f ? raw : log1pf(expf(raw));
    float A = -expf(alog[dir * Hh + hh]);
    dtb[idx] = sp;
    dab[idx] = expf(sp * A);
}

// ---------------- selective scan: one wave per (dir,b,head) ----------------
__global__ __launch_bounds__(64) void scan_kernel(const float* __restrict__ xbcc,
                                                  const float* __restrict__ dtb,
                                                  const float* __restrict__ dab,
                                                  const float* __restrict__ Dp_pair,
                                                  float* __restrict__ ybuf) {
    int h = blockIdx.x, b = blockIdx.y, dir = blockIdx.z;
    int lane = threadIdx.x;                 // lane = p (headdim)
    __shared__ __align__(16) float bsh[64];
    __shared__ __align__(16) float csh[64];
    float st[64];
    #pragma unroll
    for (int n = 0; n < 64; n++) st[n] = 0.f;
    float Dpv = Dp_pair[dir * Hh + h];
    const float* xb = xbcc + (size_t)dir * M2 * CONVD;
    for (int t = 0; t < TOUT; t++) {
        int tt = dir ? (TOUT - 1 - t) : t;
        int m = b * TOUT + tt;
        const float* row = xb + (size_t)m * CONVD;
        bsh[lane] = row[DIc + lane];
        csh[lane] = row[DIc + 64 + lane];
        __syncthreads();
        float xp = row[h * 64 + lane];
        float dtt = dtb[(size_t)(dir * M2 + m) * Hh + h];
        float da = dab[(size_t)(dir * M2 + m) * Hh + h];
        float common = dtt * xp;
        float y0 = 0.f, y1 = 0.f, y2 = 0.f, y3 = 0.f;
        #pragma unroll
        for (int n4 = 0; n4 < 16; n4++) {
            float4 bv = ((const float4*)bsh)[n4];
            float4 cv = ((const float4*)csh)[n4];
            int n = n4 * 4;
            st[n]     = st[n]     * da + common * bv.x; y0 += st[n]     * cv.x;
            st[n + 1] = st[n + 1] * da + common * bv.y; y1 += st[n + 1] * cv.y;
            st[n + 2] = st[n + 2] * da + common * bv.z; y2 += st[n + 2] * cv.z;
            st[n + 3] = st[n + 3] * da + common * bv.w; y3 += st[n + 3] * cv.w;
        }
        ybuf[((size_t)dir * M2 + m) * DIc + h * 64 + lane] = (y0 + y1) + (y2 + y3) + Dpv * xp;
        __syncthreads();
    }
}

// ---------------- gate (silu(z)) + RMSNorm, in place ----------------
__global__ __launch_bounds__(64) void grms_kernel(float* __restrict__ ybuf,
                                                  const float* __restrict__ zx2,
                                                  const float* __restrict__ nw) {
    int m = blockIdx.x, dir = blockIdx.y, lane = threadIdx.x;
    float* y = ybuf + ((size_t)dir * M2 + m) * DIc;
    const float* z = zx2 + (size_t)m * ZLD + dir * DINP;
    float g[16]; float ss = 0.f;
    #pragma unroll
    for (int j = 0; j < 16; j++) {
        int c = lane + j * 64;
        float zv = z[c];
        float gv = y[c] * (zv / (1.f + expf(-zv)));
        g[j] = gv; ss += gv * gv;
    }
    for (int o = 1; o < 64; o <<= 1) ss += __shfl_xor(ss, o);
    float sc = rsqrtf(ss * (1.f / DIc) + 1e-5f);
    #pragma unroll
    for (int j = 0; j < 16; j++) {
        int c = lane + j * 64;
        y[c] = g[j] * sc * nw[dir * DIc + c];
    }
}

// ---------------- final classifier head (fp32 output!) ----------------
__global__ __launch_bounds__(64) void outk(const float* __restrict__ h,
                                           const float* __restrict__ ow,
                                           const float* __restrict__ ob,
                                           float* __restrict__ out) {
    int m = blockIdx.x, lane = threadIdx.x;
    __shared__ float hs[DM];
    #pragma unroll
    for (int j = 0; j < 8; j++) hs[lane + j * 64] = h[(size_t)m * DM + lane + j * 64];
    __syncthreads();
    if (lane < 41) {
        float acc = ob[lane];
        for (int d = 0; d < DM; d++) acc += hs[d] * ow[lane * DM + d];
        out[(size_t)m * 41 + lane] = acc;
    }
}

// ---------------- launch ----------------
extern "C" void kernel_launch(void* const* d_in, const int* in_sizes, int n_in,
                              void* d_out, int out_size, void* d_ws, size_t ws_size,
                              hipStream_t stream) {
    const float* x        = (const float*)d_in[0];
    const int*   day_idx  = (const int*)d_in[1];
    const float* day_w    = (const float*)d_in[2];
    const float* day_b    = (const float*)d_in[3];
    const float* w1       = (const float*)d_in[4];
    const float* b1       = (const float*)d_in[5];
    const float* w2       = (const float*)d_in[6];
    const float* b2       = (const float*)d_in[7];
    const float* ln_w     = (const float*)d_in[8];
    const float* ln_b     = (const float*)d_in[9];
    const float* m_in_w   = (const float*)d_in[10];
    const float* m_conv_w = (const float*)d_in[11];
    const float* m_conv_b = (const float*)d_in[12];
    const float* m_dt     = (const float*)d_in[13];
    const float* m_Alog   = (const float*)d_in[14];
    const float* m_D      = (const float*)d_in[15];
    const float* m_norm_w = (const float*)d_in[16];
    const float* m_out_w  = (const float*)d_in[17];
    const float* out_w    = (const float*)d_in[18];
    const float* out_b    = (const float*)d_in[19];

    float* ws = (float*)d_ws;
    float* hfull = ws;                       // 4,202,496 used (reserve 4,206,592)
    float* h1    = ws + 4206592;             // 8,339,456  [2036][4096]
    float* xbcc  = ws;                       // 4,690,944  [2][2036][1152] (after h1 dead)
    float* ybuf  = ws + 4690944;             // 4,169,728  [2][2036][1024]
    float* hbuf  = ws + 12546048;            // 1,042,432  [2036][512]
    float* hn    = ws + 13588480;            // 1,042,432
    float* zx2   = ws + 14630912;            // 8,925,824  [2036][4384]
    float* dtb   = ws + 23556736;            // 65,152
    float* dab   = ws + 23621888;            // 65,152

    day_gemm<<<dim3(8, 32, 4), 256, 0, stream>>>(x, day_idx, day_w, day_b, hfull);
    copy_xt<<<32, 256, 0, stream>>>(x, hfull);
    // patch GEMM: A row m=(b,to) = contiguous 14*513 slice of hfull at b*TT*DIN + to*4*DIN
    gemm_k<1, 0><<<dim3(64, 32), 256, 0, stream>>>(hfull, w1, b1, h1,
                                                   M2, PR, 7182, TOUT, (long)TT * DIN, (long)4 * DIN, PR);
    gemm_k<0, 0><<<dim3(8, 32), 256, 0, stream>>>(h1, w2, b2, hbuf,
                                                  M2, DM, PR, 1, (long)PR, 0, DM);
    for (int i = 0; i < 5; i++) {
        ln_kernel<<<M2, 64, 0, stream>>>(hbuf, ln_w + i * DM, ln_b + i * DM, hn);
        gemm_k<0, 0><<<dim3(69, 32), 256, 0, stream>>>(hn, m_in_w + (size_t)2 * i * DINP * DM,
                                                       nullptr, zx2, M2, ZLD, DM, 1, (long)DM, 0, ZLD);
        conv_kernel<<<(2 * M2 * CONVD + 255) / 256, 256, 0, stream>>>(
            zx2, m_conv_w + (size_t)2 * i * CONVD * 4, m_conv_b + (size_t)2 * i * CONVD, xbcc);
        dt_kernel<<<(2 * M2 * Hh + 255) / 256, 256, 0, stream>>>(
            zx2, m_dt + 2 * i * Hh, m_Alog + 2 * i * Hh, dtb, dab);
        scan_kernel<<<dim3(Hh, TB, 2), 64, 0, stream>>>(xbcc, dtb, dab, m_D + 2 * i * Hh, ybuf);
        grms_kernel<<<dim3(M2, 2), 64, 0, stream>>>(ybuf, zx2, m_norm_w + (size_t)2 * i * DIc);
        gemm_k<0, 1><<<dim3(8, 32), 256, 0, stream>>>(ybuf, m_out_w + (size_t)(2 * i) * DM * DIc,
                                                      nullptr, hbuf, M2, DM, DIc, 1, (long)DIc, 0, DM);
        gemm_k<0, 1><<<dim3(8, 32), 256, 0, stream>>>(ybuf + (size_t)M2 * DIc,
                                                      m_out_w + (size_t)(2 * i + 1) * DM * DIc,
                                                      nullptr, hbuf, M2, DM, DIc, 1, (long)DIc, 0, DM);
    }
    outk<<<M2, 64, 0, stream>>>(hbuf, out_w, out_b, (float*)d_out);
}

// Round 5
// 4729.412 us; speedup vs baseline: 1.7339x; 1.7339x over previous
//
#include <hip/hip_runtime.h>
#include <hip/hip_bf16.h>

// ---------------- constants ----------------
#define TB 4
#define TT 2048
#define DIN 513
#define TOUT 509
#define M2 2036          // TB*TOUT
#define DM 512
#define PR 4096
#define DIc 1024
#define Hh 16
#define CONVD 1152
#define DINP 2192        // 2*DIc + 2*64 + 16
#define ZLD 4384         // 2*DINP (fw|bw stacked)

typedef __attribute__((ext_vector_type(8))) short s8v;   // 8 bf16 in 4 VGPRs
typedef __attribute__((ext_vector_type(4))) float f4v;   // MFMA accumulator

__device__ __forceinline__ short f2b(float f) {          // fp32 -> bf16 RNE
    unsigned u = __float_as_uint(f);
    u += 0x7fffu + ((u >> 16) & 1u);
    return (short)(u >> 16);
}

// ---------------- day-specific input transform (fp32 tiled; ~107us) ----------------
__global__ __launch_bounds__(256) void day_gemm(const float* __restrict__ x,
                                                const int* __restrict__ day_idx,
                                                const float* __restrict__ day_w,
                                                const float* __restrict__ day_b,
                                                float* __restrict__ hfull) {
    int b = blockIdx.z;
    int day = day_idx[b];
    int n0 = blockIdx.x * 64, m0 = blockIdx.y * 64;
    int tid = threadIdx.x;
    __shared__ float As[16][68], Bs[16][68];
    float acc[4][4] = {};
    int tm = tid >> 4, tn = tid & 15;
    int lrow = tid >> 2, lk = (tid & 3) * 4;
    const float* Ab = x + ((size_t)b * TT + m0) * DIN;
    const float* Bb = day_w + (size_t)day * 512 * 512;
    for (int k0 = 0; k0 < 512; k0 += 16) {
        #pragma unroll
        for (int j = 0; j < 4; j++)
            As[lk + j][lrow] = Ab[(size_t)lrow * DIN + k0 + lk + j];
        int kb = tid >> 4; int nb = (tid & 15) * 4;
        #pragma unroll
        for (int j = 0; j < 4; j++)
            Bs[kb][nb + j] = Bb[(size_t)(k0 + kb) * 512 + n0 + nb + j];
        __syncthreads();
        #pragma unroll
        for (int kk = 0; kk < 16; kk++) {
            float4 av = *(const float4*)&As[kk][tm * 4];
            float4 bv = *(const float4*)&Bs[kk][tn * 4];
            float a[4] = {av.x, av.y, av.z, av.w};
            float bb2[4] = {bv.x, bv.y, bv.z, bv.w};
            #pragma unroll
            for (int i = 0; i < 4; i++)
                #pragma unroll
                for (int j = 0; j < 4; j++) acc[i][j] += a[i] * bb2[j];
        }
        __syncthreads();
    }
    #pragma unroll
    for (int i = 0; i < 4; i++) {
        int m = m0 + tm * 4 + i;
        #pragma unroll
        for (int j = 0; j < 4; j++) {
            int n = n0 + tn * 4 + j;
            float v = acc[i][j] + day_b[day * 512 + n];
            v = v / (1.f + fabsf(v));
            hfull[((size_t)b * TT + m) * DIN + n] = v;
        }
    }
}

__global__ void copy_xt(const float* __restrict__ x, float* __restrict__ hfull) {
    int idx = blockIdx.x * 256 + threadIdx.x;
    if (idx >= TB * TT) return;
    hfull[(size_t)idx * DIN + 512] = x[(size_t)idx * DIN + 512];
}

// ---------------- MFMA bf16 GEMM: C[M,N] = act(A @ Bw^T + bias) (+= C) ----------------
// A fp32, row m at (m/rowDiv)*sOuter + (m%rowDiv)*sInner; Bw fp32 [N,K] row-major.
// 128x128 block tile, BK=32, 4 waves, each wave 64x64 via 4x4 mfma_f32_16x16x32_bf16.
template <int ACT, int ACCUM>
__global__ __launch_bounds__(256) void mgemm(const float* __restrict__ A,
                                             const float* __restrict__ Bw,
                                             const float* __restrict__ bias,
                                             float* __restrict__ C,
                                             int M, int N, int K,
                                             int rowDiv, long sOuter, long sInner, int ldc) {
    __shared__ short As[128][40];   // [row][k] bf16, +8 pad -> 80B row stride, 16B aligned frags
    __shared__ short Bs[128][40];
    int m0 = blockIdx.y * 128, n0 = blockIdx.x * 128;
    int tid = threadIdx.x;
    int wave = tid >> 6, lane = tid & 63;
    int wm = (wave & 1) * 64, wn = (wave >> 1) * 64;
    int lm = lane & 15, quad = lane >> 4, qk = quad * 8;

    // staging coords: each thread stages one row-half (16 k) of A and of B
    int r = tid >> 1;              // 0..127
    int kc = (tid & 1) * 16;       // 0 | 16
    int am = m0 + r;
    bool av = am < M;
    long abase = 0;
    if (av) abase = (long)(am / rowDiv) * sOuter + (long)(am % rowDiv) * sInner;
    int bn = n0 + r;
    bool bv = bn < N;
    long bbase = (long)(bv ? bn : 0) * K;

    f4v acc[4][4];
    #pragma unroll
    for (int i = 0; i < 4; i++)
        #pragma unroll
        for (int j = 0; j < 4; j++) acc[i][j] = (f4v){0.f, 0.f, 0.f, 0.f};

    for (int k0 = 0; k0 < K; k0 += 32) {
        int kb = k0 + kc;
        short* da = &As[r][kc];
        short* db = &Bs[r][kc];
        if (av && kb + 15 < K) {
            const float* src = A + abase + kb;        // 16B-aligned (strides mult of 4 floats)
            float4 u0 = *(const float4*)(src);
            float4 u1 = *(const float4*)(src + 4);
            float4 u2 = *(const float4*)(src + 8);
            float4 u3 = *(const float4*)(src + 12);
            da[0]=f2b(u0.x); da[1]=f2b(u0.y); da[2]=f2b(u0.z); da[3]=f2b(u0.w);
            da[4]=f2b(u1.x); da[5]=f2b(u1.y); da[6]=f2b(u1.z); da[7]=f2b(u1.w);
            da[8]=f2b(u2.x); da[9]=f2b(u2.y); da[10]=f2b(u2.z); da[11]=f2b(u2.w);
            da[12]=f2b(u3.x); da[13]=f2b(u3.y); da[14]=f2b(u3.z); da[15]=f2b(u3.w);
        } else {
            #pragma unroll
            for (int j = 0; j < 16; j++)
                da[j] = (av && kb + j < K) ? f2b(A[abase + kb + j]) : (short)0;
        }
        if (bv && kb + 15 < K) {
            const float2* src = (const float2*)(Bw + bbase + kb);  // rows only 8B-aligned
            #pragma unroll
            for (int j = 0; j < 8; j++) {
                float2 u = src[j];
                db[2 * j] = f2b(u.x); db[2 * j + 1] = f2b(u.y);
            }
        } else {
            #pragma unroll
            for (int j = 0; j < 16; j++)
                db[j] = (bv && kb + j < K) ? f2b(Bw[bbase + kb + j]) : (short)0;
        }
        __syncthreads();
        s8v af[4], bf[4];
        #pragma unroll
        for (int i = 0; i < 4; i++)
            af[i] = *(const s8v*)&As[wm + i * 16 + lm][qk];
        #pragma unroll
        for (int j = 0; j < 4; j++)
            bf[j] = *(const s8v*)&Bs[wn + j * 16 + lm][qk];
        #pragma unroll
        for (int i = 0; i < 4; i++)
            #pragma unroll
            for (int j = 0; j < 4; j++)
                acc[i][j] = __builtin_amdgcn_mfma_f32_16x16x32_bf16(af[i], bf[j], acc[i][j], 0, 0, 0);
        __syncthreads();
    }

    // epilogue: D row = quad*4+e, col = lane&15
    #pragma unroll
    for (int i = 0; i < 4; i++) {
        #pragma unroll
        for (int e = 0; e < 4; e++) {
            int m = m0 + wm + i * 16 + quad * 4 + e;
            if (m >= M) continue;
            #pragma unroll
            for (int j = 0; j < 4; j++) {
                int n = n0 + wn + j * 16 + lm;
                if (n >= N) continue;
                float v = acc[i][j][e];
                if (bias) v += bias[n];
                if (ACT == 1) v = v / (1.f + fabsf(v));
                long ci = (long)m * ldc + n;
                if (ACCUM) v += C[ci];
                C[ci] = v;
            }
        }
    }
}

// ---------------- LayerNorm ----------------
__global__ __launch_bounds__(64) void ln_kernel(const float* __restrict__ h,
                                                const float* __restrict__ w,
                                                const float* __restrict__ bgain,
                                                float* __restrict__ hn) {
    int m = blockIdx.x, lane = threadIdx.x;
    const float* row = h + (size_t)m * DM;
    float v[8]; float s = 0.f;
    #pragma unroll
    for (int j = 0; j < 8; j++) { v[j] = row[lane + j * 64]; s += v[j]; }
    for (int o = 1; o < 64; o <<= 1) s += __shfl_xor(s, o);
    float mu = s * (1.f / DM);
    float var = 0.f;
    #pragma unroll
    for (int j = 0; j < 8; j++) { float d = v[j] - mu; var += d * d; }
    for (int o = 1; o < 64; o <<= 1) var += __shfl_xor(var, o);
    float inv = rsqrtf(var * (1.f / DM) + 1e-5f);
    #pragma unroll
    for (int j = 0; j < 8; j++) {
        int c = lane + j * 64;
        hn[(size_t)m * DM + c] = (v[j] - mu) * inv * w[c] + bgain[c];
    }
}

// ---------------- depthwise conv (dir-aware) + SiLU ----------------
__global__ void conv_kernel(const float* __restrict__ zx2,
                            const float* __restrict__ cw,
                            const float* __restrict__ cb,
                            float* __restrict__ xbcc) {
    int idx = blockIdx.x * 256 + threadIdx.x;
    if (idx >= 2 * M2 * CONVD) return;
    int dir = idx / (M2 * CONVD);
    int r = idx - dir * (M2 * CONVD);
    int m = r / CONVD; int c = r - m * CONVD;
    int b = m / TOUT; int t = m - b * TOUT;
    float acc = cb[dir * CONVD + c];
    const float* w = cw + (size_t)(dir * CONVD + c) * 4;
    #pragma unroll
    for (int k = 0; k < 4; k++) {
        int tp = dir ? (t + 3 - k) : (t - 3 + k);
        if (tp >= 0 && tp < TOUT)
            acc += w[k] * zx2[(size_t)(b * TOUT + tp) * ZLD + dir * DINP + DIc + c];
    }
    xbcc[(size_t)idx] = acc / (1.f + expf(-acc));   // silu
}

// ---------------- dt softplus + dA ----------------
__global__ void dt_kernel(const float* __restrict__ zx2,
                          const float* __restrict__ dtB,
                          const float* __restrict__ alog,
                          float* __restrict__ dtb, float* __restrict__ dab) {
    int idx = blockIdx.x * 256 + threadIdx.x;
    if (idx >= 2 * M2 * Hh) return;
    int dir = idx / (M2 * Hh);
    int r = idx - dir * (M2 * Hh);
    int m = r / Hh; int hh = r - m * Hh;
    float raw = zx2[(size_t)m * ZLD + dir * DINP + DIc + CONVD + hh] + dtB[dir * Hh + hh];
    float sp = raw > 20.f ? raw : log1pf(expf(raw));
    float A = -expf(alog[dir * Hh + hh]);
    dtb[idx] = sp;
    dab[idx] = expf(sp * A);
}

// ---------------- selective scan: one wave per (dir,b,head) ----------------
__global__ __launch_bounds__(64) void scan_kernel(const float* __restrict__ xbcc,
                                                  const float* __restrict__ dtb,
                                                  const float* __restrict__ dab,
                                                  const float* __restrict__ Dp_pair,
                                                  float* __restrict__ ybuf) {
    int h = blockIdx.x, b = blockIdx.y, dir = blockIdx.z;
    int lane = threadIdx.x;                 // lane = p (headdim)
    __shared__ __align__(16) float bsh[64];
    __shared__ __align__(16) float csh[64];
    float st[64];
    #pragma unroll
    for (int n = 0; n < 64; n++) st[n] = 0.f;
    float Dpv = Dp_pair[dir * Hh + h];
    const float* xb = xbcc + (size_t)dir * M2 * CONVD;
    for (int t = 0; t < TOUT; t++) {
        int tt = dir ? (TOUT - 1 - t) : t;
        int m = b * TOUT + tt;
        const float* row = xb + (size_t)m * CONVD;
        bsh[lane] = row[DIc + lane];
        csh[lane] = row[DIc + 64 + lane];
        __syncthreads();
        float xp = row[h * 64 + lane];
        float dtt = dtb[(size_t)(dir * M2 + m) * Hh + h];
        float da = dab[(size_t)(dir * M2 + m) * Hh + h];
        float common = dtt * xp;
        float y0 = 0.f, y1 = 0.f, y2 = 0.f, y3 = 0.f;
        #pragma unroll
        for (int n4 = 0; n4 < 16; n4++) {
            float4 bv = ((const float4*)bsh)[n4];
            float4 cv = ((const float4*)csh)[n4];
            int n = n4 * 4;
            st[n]     = st[n]     * da + common * bv.x; y0 += st[n]     * cv.x;
            st[n + 1] = st[n + 1] * da + common * bv.y; y1 += st[n + 1] * cv.y;
            st[n + 2] = st[n + 2] * da + common * bv.z; y2 += st[n + 2] * cv.z;
            st[n + 3] = st[n + 3] * da + common * bv.w; y3 += st[n + 3] * cv.w;
        }
        ybuf[((size_t)dir * M2 + m) * DIc + h * 64 + lane] = (y0 + y1) + (y2 + y3) + Dpv * xp;
        __syncthreads();
    }
}

// ---------------- gate (silu(z)) + RMSNorm, in place ----------------
__global__ __launch_bounds__(64) void grms_kernel(float* __restrict__ ybuf,
                                                  const float* __restrict__ zx2,
                                                  const float* __restrict__ nw) {
    int m = blockIdx.x, dir = blockIdx.y, lane = threadIdx.x;
    float* y = ybuf + ((size_t)dir * M2 + m) * DIc;
    const float* z = zx2 + (size_t)m * ZLD + dir * DINP;
    float g[16]; float ss = 0.f;
    #pragma unroll
    for (int j = 0; j < 16; j++) {
        int c = lane + j * 64;
        float zv = z[c];
        float gv = y[c] * (zv / (1.f + expf(-zv)));
        g[j] = gv; ss += gv * gv;
    }
    for (int o = 1; o < 64; o <<= 1) ss += __shfl_xor(ss, o);
    float sc = rsqrtf(ss * (1.f / DIc) + 1e-5f);
    #pragma unroll
    for (int j = 0; j < 16; j++) {
        int c = lane + j * 64;
        y[c] = g[j] * sc * nw[dir * DIc + c];
    }
}

// ---------------- final classifier head (fp32 output) ----------------
__global__ __launch_bounds__(64) void outk(const float* __restrict__ h,
                                           const float* __restrict__ ow,
                                           const float* __restrict__ ob,
                                           float* __restrict__ out) {
    int m = blockIdx.x, lane = threadIdx.x;
    __shared__ float hs[DM];
    #pragma unroll
    for (int j = 0; j < 8; j++) hs[lane + j * 64] = h[(size_t)m * DM + lane + j * 64];
    __syncthreads();
    if (lane < 41) {
        float acc = ob[lane];
        for (int d = 0; d < DM; d++) acc += hs[d] * ow[lane * DM + d];
        out[(size_t)m * 41 + lane] = acc;
    }
}

// ---------------- launch ----------------
extern "C" void kernel_launch(void* const* d_in, const int* in_sizes, int n_in,
                              void* d_out, int out_size, void* d_ws, size_t ws_size,
                              hipStream_t stream) {
    const float* x        = (const float*)d_in[0];
    const int*   day_idx  = (const int*)d_in[1];
    const float* day_w    = (const float*)d_in[2];
    const float* day_b    = (const float*)d_in[3];
    const float* w1       = (const float*)d_in[4];
    const float* b1       = (const float*)d_in[5];
    const float* w2       = (const float*)d_in[6];
    const float* b2       = (const float*)d_in[7];
    const float* ln_w     = (const float*)d_in[8];
    const float* ln_b     = (const float*)d_in[9];
    const float* m_in_w   = (const float*)d_in[10];
    const float* m_conv_w = (const float*)d_in[11];
    const float* m_conv_b = (const float*)d_in[12];
    const float* m_dt     = (const float*)d_in[13];
    const float* m_Alog   = (const float*)d_in[14];
    const float* m_D      = (const float*)d_in[15];
    const float* m_norm_w = (const float*)d_in[16];
    const float* m_out_w  = (const float*)d_in[17];
    const float* out_w    = (const float*)d_in[18];
    const float* out_b    = (const float*)d_in[19];

    float* ws = (float*)d_ws;
    float* hfull = ws;                       // [4][2048][513]
    float* h1    = ws + 4206592;             // [2036][4096]
    float* xbcc  = ws;                       // [2][2036][1152] (after h1 dead)
    float* ybuf  = ws + 4690944;             // [2][2036][1024]
    float* hbuf  = ws + 12546048;            // [2036][512]
    float* hn    = ws + 13588480;            // [2036][512]
    float* zx2   = ws + 14630912;            // [2036][4384]
    float* dtb   = ws + 23556736;
    float* dab   = ws + 23621888;

    day_gemm<<<dim3(8, 32, 4), 256, 0, stream>>>(x, day_idx, day_w, day_b, hfull);
    copy_xt<<<32, 256, 0, stream>>>(x, hfull);
    // patch GEMM (MFMA): A row m=(b,to) = contiguous 14*513 slice of hfull
    mgemm<1, 0><<<dim3(32, 16), 256, 0, stream>>>(hfull, w1, b1, h1,
                                                  M2, PR, 7182, TOUT, (long)TT * DIN, (long)4 * DIN, PR);
    mgemm<0, 0><<<dim3(4, 16), 256, 0, stream>>>(h1, w2, b2, hbuf,
                                                 M2, DM, PR, 1, (long)PR, 0, DM);
    for (int i = 0; i < 5; i++) {
        ln_kernel<<<M2, 64, 0, stream>>>(hbuf, ln_w + i * DM, ln_b + i * DM, hn);
        mgemm<0, 0><<<dim3(35, 16), 256, 0, stream>>>(hn, m_in_w + (size_t)2 * i * DINP * DM,
                                                      nullptr, zx2, M2, ZLD, DM, 1, (long)DM, 0, ZLD);
        conv_kernel<<<(2 * M2 * CONVD + 255) / 256, 256, 0, stream>>>(
            zx2, m_conv_w + (size_t)2 * i * CONVD * 4, m_conv_b + (size_t)2 * i * CONVD, xbcc);
        dt_kernel<<<(2 * M2 * Hh + 255) / 256, 256, 0, stream>>>(
            zx2, m_dt + 2 * i * Hh, m_Alog + 2 * i * Hh, dtb, dab);
        scan_kernel<<<dim3(Hh, TB, 2), 64, 0, stream>>>(xbcc, dtb, dab, m_D + 2 * i * Hh, ybuf);
        grms_kernel<<<dim3(M2, 2), 64, 0, stream>>>(ybuf, zx2, m_norm_w + (size_t)2 * i * DIc);
        mgemm<0, 1><<<dim3(4, 16), 256, 0, stream>>>(ybuf, m_out_w + (size_t)(2 * i) * DM * DIc,
                                                     nullptr, hbuf, M2, DM, DIc, 1, (long)DIc, 0, DM);
        mgemm<0, 1><<<dim3(4, 16), 256, 0, stream>>>(ybuf + (size_t)M2 * DIc,
                                                     m_out_w + (size_t)(2 * i + 1) * DM * DIc,
                                                     nullptr, hbuf, M2, DM, DIc, 1, (long)DIc, 0, DM);
    }
    outk<<<M2, 64, 0, stream>>>(hbuf, out_w, out_b, (float*)d_out);
}

// Round 6
// 2943.484 us; speedup vs baseline: 2.7859x; 1.6067x over previous
//
#include <hip/hip_runtime.h>
#include <hip/hip_bf16.h>

// ---------------- constants ----------------
#define TB 4
#define TT 2048
#define DIN 513
#define TOUT 509
#define M2 2036          // TB*TOUT
#define DM 512
#define PR 4096
#define DIc 1024
#define Hh 16
#define CONVD 1152
#define DINP 2192        // 2*DIc + 2*64 + 16
#define ZLD 4384         // 2*DINP (fw|bw stacked)
#define LC 128           // scan chunk length
#define NC 4             // ceil(TOUT/LC)

typedef __attribute__((ext_vector_type(8))) short s8v;   // 8 bf16 in 4 VGPRs
typedef __attribute__((ext_vector_type(4))) float f4v;   // MFMA accumulator

__device__ __forceinline__ short f2b(float f) {          // fp32 -> bf16 RNE
    unsigned u = __float_as_uint(f);
    u += 0x7fffu + ((u >> 16) & 1u);
    return (short)(u >> 16);
}

// ---------------- day-specific input transform (fp32 tiled; ~107us) ----------------
__global__ __launch_bounds__(256) void day_gemm(const float* __restrict__ x,
                                                const int* __restrict__ day_idx,
                                                const float* __restrict__ day_w,
                                                const float* __restrict__ day_b,
                                                float* __restrict__ hfull) {
    int b = blockIdx.z;
    int day = day_idx[b];
    int n0 = blockIdx.x * 64, m0 = blockIdx.y * 64;
    int tid = threadIdx.x;
    __shared__ float As[16][68], Bs[16][68];
    float acc[4][4] = {};
    int tm = tid >> 4, tn = tid & 15;
    int lrow = tid >> 2, lk = (tid & 3) * 4;
    const float* Ab = x + ((size_t)b * TT + m0) * DIN;
    const float* Bb = day_w + (size_t)day * 512 * 512;
    for (int k0 = 0; k0 < 512; k0 += 16) {
        #pragma unroll
        for (int j = 0; j < 4; j++)
            As[lk + j][lrow] = Ab[(size_t)lrow * DIN + k0 + lk + j];
        int kb = tid >> 4; int nb = (tid & 15) * 4;
        #pragma unroll
        for (int j = 0; j < 4; j++)
            Bs[kb][nb + j] = Bb[(size_t)(k0 + kb) * 512 + n0 + nb + j];
        __syncthreads();
        #pragma unroll
        for (int kk = 0; kk < 16; kk++) {
            float4 av = *(const float4*)&As[kk][tm * 4];
            float4 bv = *(const float4*)&Bs[kk][tn * 4];
            float a[4] = {av.x, av.y, av.z, av.w};
            float bb2[4] = {bv.x, bv.y, bv.z, bv.w};
            #pragma unroll
            for (int i = 0; i < 4; i++)
                #pragma unroll
                for (int j = 0; j < 4; j++) acc[i][j] += a[i] * bb2[j];
        }
        __syncthreads();
    }
    #pragma unroll
    for (int i = 0; i < 4; i++) {
        int m = m0 + tm * 4 + i;
        #pragma unroll
        for (int j = 0; j < 4; j++) {
            int n = n0 + tn * 4 + j;
            float v = acc[i][j] + day_b[day * 512 + n];
            v = v / (1.f + fabsf(v));
            hfull[((size_t)b * TT + m) * DIN + n] = v;
        }
    }
}

__global__ void copy_xt(const float* __restrict__ x, float* __restrict__ hfull) {
    int idx = blockIdx.x * 256 + threadIdx.x;
    if (idx >= TB * TT) return;
    hfull[(size_t)idx * DIN + 512] = x[(size_t)idx * DIN + 512];
}

// ---------------- MFMA bf16 GEMM (128x128 tile, BK=32) ----------------
template <int ACT, int ACCUM>
__global__ __launch_bounds__(256) void mgemm(const float* __restrict__ A,
                                             const float* __restrict__ Bw,
                                             const float* __restrict__ bias,
                                             float* __restrict__ C,
                                             int M, int N, int K,
                                             int rowDiv, long sOuter, long sInner, int ldc) {
    __shared__ short As[128][40];
    __shared__ short Bs[128][40];
    int m0 = blockIdx.y * 128, n0 = blockIdx.x * 128;
    int tid = threadIdx.x;
    int wave = tid >> 6, lane = tid & 63;
    int wm = (wave & 1) * 64, wn = (wave >> 1) * 64;
    int lm = lane & 15, quad = lane >> 4, qk = quad * 8;

    int r = tid >> 1;
    int kc = (tid & 1) * 16;
    int am = m0 + r;
    bool av = am < M;
    long abase = 0;
    if (av) abase = (long)(am / rowDiv) * sOuter + (long)(am % rowDiv) * sInner;
    int bn = n0 + r;
    bool bv = bn < N;
    long bbase = (long)(bv ? bn : 0) * K;

    f4v acc[4][4];
    #pragma unroll
    for (int i = 0; i < 4; i++)
        #pragma unroll
        for (int j = 0; j < 4; j++) acc[i][j] = (f4v){0.f, 0.f, 0.f, 0.f};

    for (int k0 = 0; k0 < K; k0 += 32) {
        int kb = k0 + kc;
        short* da = &As[r][kc];
        short* db = &Bs[r][kc];
        if (av && kb + 15 < K) {
            const float* src = A + abase + kb;
            float4 u0 = *(const float4*)(src);
            float4 u1 = *(const float4*)(src + 4);
            float4 u2 = *(const float4*)(src + 8);
            float4 u3 = *(const float4*)(src + 12);
            da[0]=f2b(u0.x); da[1]=f2b(u0.y); da[2]=f2b(u0.z); da[3]=f2b(u0.w);
            da[4]=f2b(u1.x); da[5]=f2b(u1.y); da[6]=f2b(u1.z); da[7]=f2b(u1.w);
            da[8]=f2b(u2.x); da[9]=f2b(u2.y); da[10]=f2b(u2.z); da[11]=f2b(u2.w);
            da[12]=f2b(u3.x); da[13]=f2b(u3.y); da[14]=f2b(u3.z); da[15]=f2b(u3.w);
        } else {
            #pragma unroll
            for (int j = 0; j < 16; j++)
                da[j] = (av && kb + j < K) ? f2b(A[abase + kb + j]) : (short)0;
        }
        if (bv && kb + 15 < K) {
            const float2* src = (const float2*)(Bw + bbase + kb);
            #pragma unroll
            for (int j = 0; j < 8; j++) {
                float2 u = src[j];
                db[2 * j] = f2b(u.x); db[2 * j + 1] = f2b(u.y);
            }
        } else {
            #pragma unroll
            for (int j = 0; j < 16; j++)
                db[j] = (bv && kb + j < K) ? f2b(Bw[bbase + kb + j]) : (short)0;
        }
        __syncthreads();
        s8v af[4], bf[4];
        #pragma unroll
        for (int i = 0; i < 4; i++)
            af[i] = *(const s8v*)&As[wm + i * 16 + lm][qk];
        #pragma unroll
        for (int j = 0; j < 4; j++)
            bf[j] = *(const s8v*)&Bs[wn + j * 16 + lm][qk];
        #pragma unroll
        for (int i = 0; i < 4; i++)
            #pragma unroll
            for (int j = 0; j < 4; j++)
                acc[i][j] = __builtin_amdgcn_mfma_f32_16x16x32_bf16(af[i], bf[j], acc[i][j], 0, 0, 0);
        __syncthreads();
    }

    #pragma unroll
    for (int i = 0; i < 4; i++) {
        #pragma unroll
        for (int e = 0; e < 4; e++) {
            int m = m0 + wm + i * 16 + quad * 4 + e;
            if (m >= M) continue;
            #pragma unroll
            for (int j = 0; j < 4; j++) {
                int n = n0 + wn + j * 16 + lm;
                if (n >= N) continue;
                float v = acc[i][j][e];
                if (bias) v += bias[n];
                if (ACT == 1) v = v / (1.f + fabsf(v));
                long ci = (long)m * ldc + n;
                if (ACCUM) v += C[ci];
                C[ci] = v;
            }
        }
    }
}

// ---------------- LayerNorm ----------------
__global__ __launch_bounds__(64) void ln_kernel(const float* __restrict__ h,
                                                const float* __restrict__ w,
                                                const float* __restrict__ bgain,
                                                float* __restrict__ hn) {
    int m = blockIdx.x, lane = threadIdx.x;
    const float* row = h + (size_t)m * DM;
    float v[8]; float s = 0.f;
    #pragma unroll
    for (int j = 0; j < 8; j++) { v[j] = row[lane + j * 64]; s += v[j]; }
    for (int o = 1; o < 64; o <<= 1) s += __shfl_xor(s, o);
    float mu = s * (1.f / DM);
    float var = 0.f;
    #pragma unroll
    for (int j = 0; j < 8; j++) { float d = v[j] - mu; var += d * d; }
    for (int o = 1; o < 64; o <<= 1) var += __shfl_xor(var, o);
    float inv = rsqrtf(var * (1.f / DM) + 1e-5f);
    #pragma unroll
    for (int j = 0; j < 8; j++) {
        int c = lane + j * 64;
        hn[(size_t)m * DM + c] = (v[j] - mu) * inv * w[c] + bgain[c];
    }
}

// ---------------- depthwise conv (dir-aware) + SiLU ----------------
__global__ void conv_kernel(const float* __restrict__ zx2,
                            const float* __restrict__ cw,
                            const float* __restrict__ cb,
                            float* __restrict__ xbcc) {
    int idx = blockIdx.x * 256 + threadIdx.x;
    if (idx >= 2 * M2 * CONVD) return;
    int dir = idx / (M2 * CONVD);
    int r = idx - dir * (M2 * CONVD);
    int m = r / CONVD; int c = r - m * CONVD;
    int b = m / TOUT; int t = m - b * TOUT;
    float acc = cb[dir * CONVD + c];
    const float* w = cw + (size_t)(dir * CONVD + c) * 4;
    #pragma unroll
    for (int k = 0; k < 4; k++) {
        int tp = dir ? (t + 3 - k) : (t - 3 + k);
        if (tp >= 0 && tp < TOUT)
            acc += w[k] * zx2[(size_t)(b * TOUT + tp) * ZLD + dir * DINP + DIc + c];
    }
    xbcc[(size_t)idx] = acc / (1.f + expf(-acc));   // silu
}

// ---------------- dt softplus + dA ----------------
__global__ void dt_kernel(const float* __restrict__ zx2,
                          const float* __restrict__ dtB,
                          const float* __restrict__ alog,
                          float* __restrict__ dtb, float* __restrict__ dab) {
    int idx = blockIdx.x * 256 + threadIdx.x;
    if (idx >= 2 * M2 * Hh) return;
    int dir = idx / (M2 * Hh);
    int r = idx - dir * (M2 * Hh);
    int m = r / Hh; int hh = r - m * Hh;
    float raw = zx2[(size_t)m * ZLD + dir * DINP + DIc + CONVD + hh] + dtB[dir * Hh + hh];
    float sp = raw > 20.f ? raw : log1pf(expf(raw));
    float A = -expf(alog[dir * Hh + hh]);
    dtb[idx] = sp;
    dab[idx] = expf(sp * A);
}

// ---------------- chunked selective scan ----------------
// Pass 1: per-chunk local scan (H_in = 0), one wave per (h, chunk, b, dir).
// Stores y_local (incl. D*x), chunk-end local state to Hbuf, cumulative decay Pcum.
__global__ __launch_bounds__(64) void scan_local(const float* __restrict__ xbcc,
                                                 const float* __restrict__ dtb,
                                                 const float* __restrict__ dab,
                                                 const float* __restrict__ Dp_pair,
                                                 float* __restrict__ ybuf,
                                                 float* __restrict__ Hbuf,
                                                 float* __restrict__ Pcum) {
    int h = blockIdx.x & 15, chunk = blockIdx.x >> 4;
    int b = blockIdx.y, dir = blockIdx.z;
    int lane = threadIdx.x;                 // lane = p (headdim)
    int s0 = chunk * LC;
    int s1 = min(s0 + LC, TOUT);
    __shared__ __align__(16) float bsh[2][64];
    __shared__ __align__(16) float csh[2][64];
    float st[64];
    #pragma unroll
    for (int n = 0; n < 64; n++) st[n] = 0.f;
    float Dpv = Dp_pair[dir * Hh + h];
    const float* xb = xbcc + (size_t)dir * M2 * CONVD;
    long dtbase = (size_t)(dir * M2 + b * TOUT) * Hh + h;   // + tt*Hh
    int id = (dir * TB + b) * Hh + h;
    float* pcm = Pcum + (size_t)id * TOUT;

    // prologue: load s0
    int tt0 = dir ? (TOUT - 1 - s0) : s0;
    const float* row0 = xb + (size_t)(b * TOUT + tt0) * CONVD;
    float bcur = row0[DIc + lane];
    float ccur = row0[DIc + 64 + lane];
    float xcur = row0[h * 64 + lane];
    float dtcur = dtb[dtbase + (long)tt0 * Hh];
    float dacur = dab[dtbase + (long)tt0 * Hh];
    float P = 1.f;

    for (int s = s0; s < s1; s++) {
        int pb = s & 1;
        bsh[pb][lane] = bcur;
        csh[pb][lane] = ccur;
        float xp = xcur, dtt = dtcur, da = dacur;
        __syncthreads();
        // prefetch s+1 (loads overlap compute below)
        if (s + 1 < s1) {
            int tn = dir ? (TOUT - 1 - (s + 1)) : (s + 1);
            const float* rown = xb + (size_t)(b * TOUT + tn) * CONVD;
            bcur = rown[DIc + lane];
            ccur = rown[DIc + 64 + lane];
            xcur = rown[h * 64 + lane];
            dtcur = dtb[dtbase + (long)tn * Hh];
            dacur = dab[dtbase + (long)tn * Hh];
        }
        float common = dtt * xp;
        float y0 = 0.f, y1 = 0.f, y2 = 0.f, y3 = 0.f;
        #pragma unroll
        for (int n4 = 0; n4 < 16; n4++) {
            float4 bv = ((const float4*)bsh[pb])[n4];
            float4 cv = ((const float4*)csh[pb])[n4];
            int n = n4 * 4;
            st[n]     = st[n]     * da + common * bv.x; y0 += st[n]     * cv.x;
            st[n + 1] = st[n + 1] * da + common * bv.y; y1 += st[n + 1] * cv.y;
            st[n + 2] = st[n + 2] * da + common * bv.z; y2 += st[n + 2] * cv.z;
            st[n + 3] = st[n + 3] * da + common * bv.w; y3 += st[n + 3] * cv.w;
        }
        int tt = dir ? (TOUT - 1 - s) : s;
        int m = b * TOUT + tt;
        ybuf[((size_t)dir * M2 + m) * DIc + h * 64 + lane] = (y0 + y1) + (y2 + y3) + Dpv * xp;
        P *= da;
        if (lane == 0) pcm[s] = P;
    }
    // store local end state: Hbuf[id][chunk][p=lane][n]
    float* Ho = Hbuf + (((size_t)id * NC + chunk) * 64 + lane) * 64;
    #pragma unroll
    for (int n4 = 0; n4 < 16; n4++) {
        ((float4*)Ho)[n4] = (float4){st[n4 * 4], st[n4 * 4 + 1], st[n4 * 4 + 2], st[n4 * 4 + 3]};
    }
}

// Pass 2: sequential combine over NC chunks. Rewrites Hbuf[id][c] with the
// INCOMING state for chunk c: Hin[0]=0; Hin[c+1] = Hout[c] + Pend[c]*Hin[c].
__global__ __launch_bounds__(64) void scan_combine(float* __restrict__ Hbuf,
                                                   const float* __restrict__ Pcum) {
    int id = blockIdx.x;           // (dir*TB+b)*Hh+h, 128 total
    int lane = threadIdx.x;        // p
    float Hin[64];
    #pragma unroll
    for (int n = 0; n < 64; n++) Hin[n] = 0.f;
    const float* pcm = Pcum + (size_t)id * TOUT;
    for (int c = 0; c < NC; c++) {
        float* Hp = Hbuf + (((size_t)id * NC + c) * 64 + lane) * 64;
        float Hout[64];
        #pragma unroll
        for (int n4 = 0; n4 < 16; n4++) {
            float4 v = ((const float4*)Hp)[n4];
            Hout[n4 * 4] = v.x; Hout[n4 * 4 + 1] = v.y;
            Hout[n4 * 4 + 2] = v.z; Hout[n4 * 4 + 3] = v.w;
        }
        #pragma unroll
        for (int n4 = 0; n4 < 16; n4++)
            ((float4*)Hp)[n4] = (float4){Hin[n4 * 4], Hin[n4 * 4 + 1], Hin[n4 * 4 + 2], Hin[n4 * 4 + 3]};
        int send = min((c + 1) * LC, TOUT) - 1;
        float Pe = pcm[send];
        #pragma unroll
        for (int n = 0; n < 64; n++) Hin[n] = Hout[n] + Pe * Hin[n];
    }
}

// Pass 3: correction y_s += P(s) * (C_s · Hin[c(s)]). Chunk 0 has Hin=0 (skipped).
// One wave per (h, chunk-quarter); iterations over s are independent.
__global__ __launch_bounds__(64) void scan_fix(const float* __restrict__ xbcc,
                                               const float* __restrict__ Hbuf,
                                               const float* __restrict__ Pcum,
                                               float* __restrict__ ybuf) {
    int h = blockIdx.x & 15;
    int q = (blockIdx.x >> 4) & 3;
    int c = 1 + (blockIdx.x >> 6);
    int b = blockIdx.y, dir = blockIdx.z, lane = threadIdx.x;
    int s0 = c * LC;
    int s1 = min(s0 + LC, TOUT);
    int sa = s0 + q * (LC / 4);
    int se = min(sa + LC / 4, s1);
    if (sa >= se) return;
    int id = (dir * TB + b) * Hh + h;
    float Hr[64];
    const float* Hp = Hbuf + (((size_t)id * NC + c) * 64 + lane) * 64;
    #pragma unroll
    for (int n4 = 0; n4 < 16; n4++) {
        float4 v = ((const float4*)Hp)[n4];
        Hr[n4 * 4] = v.x; Hr[n4 * 4 + 1] = v.y; Hr[n4 * 4 + 2] = v.z; Hr[n4 * 4 + 3] = v.w;
    }
    const float* pcm = Pcum + (size_t)id * TOUT;
    const float* xb = xbcc + (size_t)dir * M2 * CONVD;
    for (int s = sa; s < se; s++) {
        int tt = dir ? (TOUT - 1 - s) : s;
        const float4* crow = (const float4*)(xb + (size_t)(b * TOUT + tt) * CONVD + DIc + 64);
        float acc = 0.f;
        #pragma unroll
        for (int n4 = 0; n4 < 16; n4++) {
            float4 cv = crow[n4];                 // broadcast across lanes
            acc += Hr[n4 * 4] * cv.x + Hr[n4 * 4 + 1] * cv.y
                 + Hr[n4 * 4 + 2] * cv.z + Hr[n4 * 4 + 3] * cv.w;
        }
        size_t yi = ((size_t)dir * M2 + b * TOUT + tt) * DIc + h * 64 + lane;
        ybuf[yi] += pcm[s] * acc;
    }
}

// ---------------- gate (silu(z)) + RMSNorm, in place ----------------
__global__ __launch_bounds__(64) void grms_kernel(float* __restrict__ ybuf,
                                                  const float* __restrict__ zx2,
                                                  const float* __restrict__ nw) {
    int m = blockIdx.x, dir = blockIdx.y, lane = threadIdx.x;
    float* y = ybuf + ((size_t)dir * M2 + m) * DIc;
    const float* z = zx2 + (size_t)m * ZLD + dir * DINP;
    float g[16]; float ss = 0.f;
    #pragma unroll
    for (int j = 0; j < 16; j++) {
        int c = lane + j * 64;
        float zv = z[c];
        float gv = y[c] * (zv / (1.f + expf(-zv)));
        g[j] = gv; ss += gv * gv;
    }
    for (int o = 1; o < 64; o <<= 1) ss += __shfl_xor(ss, o);
    float sc = rsqrtf(ss * (1.f / DIc) + 1e-5f);
    #pragma unroll
    for (int j = 0; j < 16; j++) {
        int c = lane + j * 64;
        y[c] = g[j] * sc * nw[dir * DIc + c];
    }
}

// ---------------- final classifier head (fp32 output) ----------------
__global__ __launch_bounds__(64) void outk(const float* __restrict__ h,
                                           const float* __restrict__ ow,
                                           const float* __restrict__ ob,
                                           float* __restrict__ out) {
    int m = blockIdx.x, lane = threadIdx.x;
    __shared__ float hs[DM];
    #pragma unroll
    for (int j = 0; j < 8; j++) hs[lane + j * 64] = h[(size_t)m * DM + lane + j * 64];
    __syncthreads();
    if (lane < 41) {
        float acc = ob[lane];
        for (int d = 0; d < DM; d++) acc += hs[d] * ow[lane * DM + d];
        out[(size_t)m * 41 + lane] = acc;
    }
}

// ---------------- launch ----------------
extern "C" void kernel_launch(void* const* d_in, const int* in_sizes, int n_in,
                              void* d_out, int out_size, void* d_ws, size_t ws_size,
                              hipStream_t stream) {
    const float* x        = (const float*)d_in[0];
    const int*   day_idx  = (const int*)d_in[1];
    const float* day_w    = (const float*)d_in[2];
    const float* day_b    = (const float*)d_in[3];
    const float* w1       = (const float*)d_in[4];
    const float* b1       = (const float*)d_in[5];
    const float* w2       = (const float*)d_in[6];
    const float* b2       = (const float*)d_in[7];
    const float* ln_w     = (const float*)d_in[8];
    const float* ln_b     = (const float*)d_in[9];
    const float* m_in_w   = (const float*)d_in[10];
    const float* m_conv_w = (const float*)d_in[11];
    const float* m_conv_b = (const float*)d_in[12];
    const float* m_dt     = (const float*)d_in[13];
    const float* m_Alog   = (const float*)d_in[14];
    const float* m_D      = (const float*)d_in[15];
    const float* m_norm_w = (const float*)d_in[16];
    const float* m_out_w  = (const float*)d_in[17];
    const float* out_w    = (const float*)d_in[18];
    const float* out_b    = (const float*)d_in[19];

    float* ws = (float*)d_ws;
    float* hfull = ws;                       // [4][2048][513]
    float* h1    = ws + 4206592;             // [2036][4096] (dead after w2 gemm)
    float* xbcc  = ws;                       // [2][2036][1152] (overlays hfull, dead by then)
    float* ybuf  = ws + 4690944;             // [2][2036][1024]
    float* Hbuf  = ws + 8860672;             // [128][NC][64][64] = 2,097,152 (in dead h1 gap)
    float* Pcum  = ws + 10957824;            // [128][509] = 65,152
    float* hbuf  = ws + 12546048;            // [2036][512]
    float* hn    = ws + 13588480;            // [2036][512]
    float* zx2   = ws + 14630912;            // [2036][4384]
    float* dtb   = ws + 23556736;
    float* dab   = ws + 23621888;

    day_gemm<<<dim3(8, 32, 4), 256, 0, stream>>>(x, day_idx, day_w, day_b, hfull);
    copy_xt<<<32, 256, 0, stream>>>(x, hfull);
    mgemm<1, 0><<<dim3(32, 16), 256, 0, stream>>>(hfull, w1, b1, h1,
                                                  M2, PR, 7182, TOUT, (long)TT * DIN, (long)4 * DIN, PR);
    mgemm<0, 0><<<dim3(4, 16), 256, 0, stream>>>(h1, w2, b2, hbuf,
                                                 M2, DM, PR, 1, (long)PR, 0, DM);
    for (int i = 0; i < 5; i++) {
        ln_kernel<<<M2, 64, 0, stream>>>(hbuf, ln_w + i * DM, ln_b + i * DM, hn);
        mgemm<0, 0><<<dim3(35, 16), 256, 0, stream>>>(hn, m_in_w + (size_t)2 * i * DINP * DM,
                                                      nullptr, zx2, M2, ZLD, DM, 1, (long)DM, 0, ZLD);
        conv_kernel<<<(2 * M2 * CONVD + 255) / 256, 256, 0, stream>>>(
            zx2, m_conv_w + (size_t)2 * i * CONVD * 4, m_conv_b + (size_t)2 * i * CONVD, xbcc);
        dt_kernel<<<(2 * M2 * Hh + 255) / 256, 256, 0, stream>>>(
            zx2, m_dt + 2 * i * Hh, m_Alog + 2 * i * Hh, dtb, dab);
        scan_local<<<dim3(Hh * NC, TB, 2), 64, 0, stream>>>(xbcc, dtb, dab, m_D + 2 * i * Hh,
                                                            ybuf, Hbuf, Pcum);
        scan_combine<<<128, 64, 0, stream>>>(Hbuf, Pcum);
        scan_fix<<<dim3(Hh * 4 * (NC - 1), TB, 2), 64, 0, stream>>>(xbcc, Hbuf, Pcum, ybuf);
        grms_kernel<<<dim3(M2, 2), 64, 0, stream>>>(ybuf, zx2, m_norm_w + (size_t)2 * i * DIc);
        mgemm<0, 1><<<dim3(4, 16), 256, 0, stream>>>(ybuf, m_out_w + (size_t)(2 * i) * DM * DIc,
                                                     nullptr, hbuf, M2, DM, DIc, 1, (long)DIc, 0, DM);
        mgemm<0, 1><<<dim3(4, 16), 256, 0, stream>>>(ybuf + (size_t)M2 * DIc,
                                                     m_out_w + (size_t)(2 * i + 1) * DM * DIc,
                                                     nullptr, hbuf, M2, DM, DIc, 1, (long)DIc, 0, DM);
    }
    outk<<<M2, 64, 0, stream>>>(hbuf, out_w, out_b, (float*)d_out);
}